// Round 18
// baseline (590.346 us; speedup 1.0000x reference)
//
#include <hip/hip_runtime.h>
#include <math.h>

// Shapes (fixed by setup_inputs)
#define BATCH 8
#define TSEQ 2048
#define CIN 3
#define WIN 5
#define LSEQ 2044          // T - WIN + 1
#define LH 2045            // LSEQ + 1 (cls token appended)
#define LHP 2048           // padded token rows for bf16 h buffers
#define DIM 128
#define DEPTH 4
#define DIN 256            // d_inner
#define NH 4               // heads
#define PDIM 64            // headdim
#define NSTATE 64          // d_state
#define CONVD 384          // d_inner + 2*d_state
#define DPROJ 644          // 2*d_inner + 2*d_state + nheads
#define NJT 41             // j-tiles of 16 (41*16 = 656 >= 644)
#define QC 64              // chunk length
#define NCH 32             // number of chunks
#define LDS2 68            // padded LDS row stride (shorts, 64-col frag buffers)
#define LDSY 264           // padded LDS row stride (shorts, 256-col k_out buffer)
#define LDSH 136           // padded LDS row stride (shorts, 128-col h tile)
#define FTR 32             // tokens per k_front block

typedef __attribute__((ext_vector_type(8))) short bf16x8;
typedef __attribute__((ext_vector_type(4))) float f32x4;
union Frag8 { bf16x8 v; uint2 u[2]; };

__device__ __forceinline__ float sigmoidf_(float x){ return 1.f/(1.f+__expf(-x)); }
__device__ __forceinline__ float siluf_(float x){ return x*sigmoidf_(x); }
__device__ __forceinline__ unsigned short f2bf(float f){   // RNE fp32->bf16
  unsigned int u = __float_as_uint(f);
  return (unsigned short)((u + 0x7FFFu + ((u >> 16) & 1u)) >> 16);
}
__device__ __forceinline__ float bf2f(unsigned short u){
  return __uint_as_float(((unsigned int)u) << 16);
}
__device__ __forceinline__ unsigned int pack2(float a, float b){  // [lo addr]=a
  return (unsigned int)f2bf(a) | ((unsigned int)f2bf(b) << 16);
}
__device__ __forceinline__ unsigned int pack2lo(float a, float b){
  float ra = a - bf2f(f2bf(a)), rb = b - bf2f(f2bf(b));
  return (unsigned int)f2bf(ra) | ((unsigned int)f2bf(rb) << 16);
}
__device__ __forceinline__ bf16x8 ldfrag(const unsigned short* base, int off){
  Frag8 f;
  f.u[0] = *(const uint2*)(base + off);
  f.u[1] = *(const uint2*)(base + off + 4);
  return f.v;
}

// inw -> MFMA-fragment-order bf16 hi/lo: wS[layer][jt][kb][lane][8].
__global__ void __launch_bounds__(256) k_cast_w(
    const float* __restrict__ w, unsigned short* __restrict__ wH,
    unsigned short* __restrict__ wL) {
  int gid = blockIdx.x*256 + threadIdx.x;     // [ly][jt][kb][lane]
  if (gid >= DEPTH*NJT*4*64) return;
  int lane = gid & 63;
  int kb = (gid >> 6) & 3;
  int jt = (gid >> 8) % NJT;
  int ly = gid / (NJT*4*64);
  int m = lane & 15, q = lane >> 4;
  int j = jt*16 + m;
  int k = kb*32 + q*8;
  unsigned short hi[8], lo[8];
  if (j < DPROJ) {
    const float* src = w + ((size_t)ly*DPROJ + j)*DIM + k;
#pragma unroll
    for (int i = 0; i < 8; ++i) {
      float v = src[i];
      hi[i] = f2bf(v);
      lo[i] = f2bf(v - bf2f(hi[i]));
    }
  } else {
#pragma unroll
    for (int i = 0; i < 8; ++i) { hi[i] = 0; lo[i] = 0; }
  }
  size_t dst = (size_t)gid*8;
  *(uint4*)(wH + dst) = *(const uint4*)hi;
  *(uint4*)(wL + dst) = *(const uint4*)lo;
}

// ow (4,128,256) -> fragment-order bf16 hi/lo: oS[layer][jt(8)][kb(8)][lane][8].
__global__ void __launch_bounds__(256) k_cast_ow(
    const float* __restrict__ ow, unsigned short* __restrict__ oH,
    unsigned short* __restrict__ oL) {
  int gid = blockIdx.x*256 + threadIdx.x;
  if (gid >= DEPTH*8*8*64) return;
  int lane = gid & 63;
  int kb = (gid >> 6) & 7;
  int jt = (gid >> 9) & 7;
  int ly = gid >> 12;
  int m = lane & 15, q = lane >> 4;
  int j = jt*16 + m;
  int k = kb*32 + q*8;
  const float* src = ow + ((size_t)ly*DIM + j)*DIN + k;
  unsigned short hi[8], lo[8];
#pragma unroll
  for (int i = 0; i < 8; ++i) {
    float v = src[i];
    hi[i] = f2bf(v);
    lo[i] = f2bf(v - bf2f(hi[i]));
  }
  size_t dst = (size_t)gid*8;
  *(uint4*)(oH + dst) = *(const uint4*)hi;
  *(uint4*)(oL + dst) = *(const uint4*)lo;
}

// ---------------------------------------------------------------- front MLP (writes hi/lo only)
__global__ void __launch_bounds__(256) k_front(
    const float* __restrict__ x, const float* __restrict__ w1,
    const float* __restrict__ b1, const float* __restrict__ w2,
    const float* __restrict__ b2, const float* __restrict__ cls,
    unsigned short* __restrict__ hH, unsigned short* __restrict__ hL) {
  int t = threadIdx.x;
  if (blockIdx.x == BATCH*64) {              // cls rows
    if (t < DIM) {
      float cv = cls[t];
      unsigned short hi = f2bf(cv);
      unsigned short lo = f2bf(cv - bf2f(hi));
      for (int b = 0; b < BATCH; ++b) {
        hH[((size_t)b*LHP + LSEQ)*DIM + t] = hi;
        hL[((size_t)b*LHP + LSEQ)*DIM + t] = lo;
      }
    }
    return;
  }
  int b = blockIdx.x >> 6;
  int c0 = (blockIdx.x & 63) * FTR;
  __shared__ float xs[(FTR+4)*CIN];
  __shared__ float w1s[DIM*17];
  __shared__ __align__(16) float h1s[FTR][DIM];
  __shared__ float part[FTR][DIM][2];
  for (int i = t; i < (FTR+4)*CIN; i += 256) {
    int row = c0 + i/3, ch = i - (i/3)*3;
    xs[i] = (row < TSEQ) ? x[(size_t)b*TSEQ*CIN + (size_t)row*CIN + ch] : 0.f;
  }
  for (int i = t; i < DIM*15; i += 256) {
    int j = i/15, k = i - j*15;
    w1s[j*17+k] = w1[i];
  }
  __syncthreads();
  {
    int j = t & 127, rh = t >> 7;
    float bias = b1[j];
    const float* wr = &w1s[j*17];
    for (int r = rh*16; r < rh*16+16; ++r) {
      float a = bias;
#pragma unroll
      for (int k = 0; k < 15; ++k) a += xs[r*3+k]*wr[k];
      h1s[r][j] = 0.5f*a*(1.f + erff(a*0.70710678118654752f));  // exact gelu
    }
  }
  __syncthreads();
  {
    int j = t & 127, hf = t >> 7;
    float4 wv[16];
    const float4* w2r = (const float4*)(w2 + (size_t)j*DIM + hf*64);
#pragma unroll
    for (int k4 = 0; k4 < 16; ++k4) wv[k4] = w2r[k4];
#pragma unroll 2
    for (int r = 0; r < FTR; ++r) {
      const float4* hr = (const float4*)&h1s[r][hf*64];
      float acc = 0.f;
#pragma unroll
      for (int k4 = 0; k4 < 16; ++k4) {
        float4 hv = hr[k4];
        acc += wv[k4].x*hv.x + wv[k4].y*hv.y + wv[k4].z*hv.z + wv[k4].w*hv.w;
      }
      part[r][j][hf] = acc;
    }
  }
  __syncthreads();
  if (t < DIM) {
    float bias = b2[t];
    for (int r = 0; r < FTR; ++r) {
      int l = c0 + r;
      if (l < LSEQ) {
        float val = part[r][t][0] + part[r][t][1] + bias;
        unsigned short hi = f2bf(val);
        hH[((size_t)b*LHP + l)*DIM + t] = hi;
        hL[((size_t)b*LHP + l)*DIM + t] = f2bf(val - bf2f(hi));
      }
    }
  }
}

// ---------------------------------------------------------------- in_proj via bf16x3 MFMA
// (layer 0 only — layers 1..3 are fused into k_out_fused)
__global__ void __launch_bounds__(256) k_inproj_mfma(
    const unsigned short* __restrict__ hH, const unsigned short* __restrict__ hL,
    const unsigned short* __restrict__ wH, const unsigned short* __restrict__ wL,
    const float* __restrict__ dtb, float* __restrict__ zx) {
  int b = blockIdx.x >> 6;
  int r = blockIdx.x & 63;
  int lb = r >> 1, jh = r & 1;
  int wv = threadIdx.x >> 6, lane = threadIdx.x & 63;
  int l0 = lb*64 + wv*16;
  int m = lane & 15, q = lane >> 4;
  size_t hoff = ((size_t)b*LHP + (l0 + m))*DIM + q*8;
  bf16x8 ah[4], al[4];
#pragma unroll
  for (int kb = 0; kb < 4; ++kb) {
    ah[kb] = *(const bf16x8*)(hH + hoff + kb*32);
    al[kb] = *(const bf16x8*)(hL + hoff + kb*32);
  }
  int jt0 = jh ? 21 : 0, jtn = jh ? NJT : 21;
#pragma unroll 2
  for (int jt = jt0; jt < jtn; ++jt) {
    size_t woff = (((size_t)jt*4)*64 + lane)*8;
    bf16x8 bh[4], bl[4];
#pragma unroll
    for (int kb = 0; kb < 4; ++kb) {
      bh[kb] = *(const bf16x8*)(wH + woff + (size_t)kb*64*8);  // coalesced
      bl[kb] = *(const bf16x8*)(wL + woff + (size_t)kb*64*8);
    }
    f32x4 acc = {0.f, 0.f, 0.f, 0.f};
#pragma unroll
    for (int kb = 0; kb < 4; ++kb)
      acc = __builtin_amdgcn_mfma_f32_16x16x32_bf16(al[kb], bh[kb], acc, 0, 0, 0);
#pragma unroll
    for (int kb = 0; kb < 4; ++kb)
      acc = __builtin_amdgcn_mfma_f32_16x16x32_bf16(ah[kb], bl[kb], acc, 0, 0, 0);
#pragma unroll
    for (int kb = 0; kb < 4; ++kb)
      acc = __builtin_amdgcn_mfma_f32_16x16x32_bf16(ah[kb], bh[kb], acc, 0, 0, 0);
    int jj = jt*16 + m;                     // D col = lane&15
    if (jj < DPROJ) {
      bool isdt = (jj >= 640);
      float bias = isdt ? dtb[jj - 640] : 0.f;
#pragma unroll
      for (int rr = 0; rr < 4; ++rr) {
        int tok = l0 + q*4 + rr;            // D row = q*4 + reg
        if (tok < LH) {
          float v = acc[rr];
          if (isdt) { v += bias; v = (v > 20.f) ? v : log1pf(__expf(v)); }
          zx[((size_t)b*LH + tok)*DPROJ + jj] = v;
        }
      }
    }
  }
}

// ---------------------------------------------------------------- causal dwconv + silu
__global__ void k_conv(const float* __restrict__ zx, const float* __restrict__ cw,
                       const float* __restrict__ cb, float* __restrict__ xbc) {
  size_t idx = (size_t)blockIdx.x*blockDim.x + threadIdx.x;
  const size_t total = (size_t)BATCH*LH*(CONVD/4);
  if (idx >= total) return;
  int c4 = (int)(idx % (CONVD/4)) * 4;
  size_t bl = idx / (CONVD/4);
  int l = (int)(bl % LH); int b = (int)(bl / LH);
  float4 w0 = *(const float4*)(cw + (c4+0)*4);
  float4 w1 = *(const float4*)(cw + (c4+1)*4);
  float4 w2 = *(const float4*)(cw + (c4+2)*4);
  float4 w3 = *(const float4*)(cw + (c4+3)*4);
  float4 a = *(const float4*)(cb + c4);
#pragma unroll
  for (int k = 0; k < 4; ++k) {
    int tin = l - 3 + k;
    if (tin >= 0) {
      float4 v = *(const float4*)(zx + ((size_t)b*LH + tin)*DPROJ + DIN + c4);
      a.x += v.x * ((const float*)&w0)[k];
      a.y += v.y * ((const float*)&w1)[k];
      a.z += v.z * ((const float*)&w2)[k];
      a.w += v.w * ((const float*)&w3)[k];
    }
  }
  float4 o;
  o.x = siluf_(a.x); o.y = siluf_(a.y); o.z = siluf_(a.z); o.w = siluf_(a.w);
  *(float4*)(xbc + ((size_t)b*LH + l)*CONVD + c4) = o;
}

// ---------------------------------------------------------------- chunked SSD, phase A
// G[n][p] = sum_s (coef_s*B_s[n]) * X_s[p]  via bf16x3 MFMA. (R16-verified.)
__global__ void __launch_bounds__(256) k_chunk_state(
    const float* __restrict__ zx, const float* __restrict__ xbc,
    const float* __restrict__ A_log, float* __restrict__ G, float* __restrict__ dec) {
  int blk = blockIdx.x;
  int c = blk & (NCH-1), hd = (blk >> 5) & 3, b = blk >> 7;
  int t0 = c*QC;
  int tid = threadIdx.x;
  int wv = tid >> 6, lane = tid & 63;
  int m = lane & 15, q = lane >> 4;
  float A = -__expf(A_log[hd]);
  __shared__ __align__(16) unsigned short BcH[QC*LDS2], BcL[QC*LDS2]; // [n][s]
  __shared__ __align__(16) unsigned short XtH[QC*LDS2], XtL[QC*LDS2]; // [p][s]
  __shared__ float coef[QC];
  if (tid < 64) {
    int tg = t0 + tid;
    float dtv = (tg < LH) ? zx[((size_t)b*LH + tg)*DPROJ + 640 + hd] : 0.f;
    float s = dtv;
#pragma unroll
    for (int off = 1; off < 64; off <<= 1) {
      float u = __shfl_up(s, off);
      if (tid >= off) s += u;
    }
    float cq = __shfl(s, 63);
    coef[tid] = __expf(A*(cq - s)) * dtv;
    if (tid == 63) dec[blk] = __expf(A * s);
  }
  __syncthreads();
  for (int i = tid; i < 2048; i += 256) {
    int n = i & 63, s2 = (i >> 6)*2;
    int tg0 = t0 + s2, tg1 = t0 + s2 + 1;
    float b0 = 0.f, b1 = 0.f, x0 = 0.f, x1 = 0.f;
    if (tg0 < LH) {
      size_t row = ((size_t)b*LH + tg0)*CONVD;
      b0 = xbc[row + DIN + n] * coef[s2];
      x0 = xbc[row + hd*PDIM + n];
    }
    if (tg1 < LH) {
      size_t row = ((size_t)b*LH + tg1)*CONVD;
      b1 = xbc[row + DIN + n] * coef[s2+1];
      x1 = xbc[row + hd*PDIM + n];
    }
    int o = n*LDS2 + s2;
    *(unsigned int*)(BcH + o) = pack2(b0, b1);
    *(unsigned int*)(BcL + o) = pack2lo(b0, b1);
    *(unsigned int*)(XtH + o) = pack2(x0, x1);
    *(unsigned int*)(XtL + o) = pack2lo(x0, x1);
  }
  __syncthreads();
  bf16x8 ah[2], al[2];
#pragma unroll
  for (int kc = 0; kc < 2; ++kc) {
    int off = (wv*16 + m)*LDS2 + kc*32 + q*8;
    ah[kc] = ldfrag(BcH, off);
    al[kc] = ldfrag(BcL, off);
  }
#pragma unroll
  for (int nt = 0; nt < 4; ++nt) {
    f32x4 acc = {0.f,0.f,0.f,0.f};
#pragma unroll
    for (int kc = 0; kc < 2; ++kc) {
      int off = (nt*16 + m)*LDS2 + kc*32 + q*8;
      bf16x8 xh = ldfrag(XtH, off), xl = ldfrag(XtL, off);
      acc = __builtin_amdgcn_mfma_f32_16x16x32_bf16(al[kc], xh, acc, 0, 0, 0);
      acc = __builtin_amdgcn_mfma_f32_16x16x32_bf16(ah[kc], xl, acc, 0, 0, 0);
      acc = __builtin_amdgcn_mfma_f32_16x16x32_bf16(ah[kc], xh, acc, 0, 0, 0);
    }
    int p = nt*16 + m;
#pragma unroll
    for (int r = 0; r < 4; ++r) {
      int n = wv*16 + q*4 + r;
      G[(size_t)blk*4096 + n*64 + p] = acc[r];
    }
  }
}

// ---------------------------------------------------------------- phase B: inter-chunk
__global__ void __launch_bounds__(256) k_combine(
    const float* __restrict__ G, const float* __restrict__ dec, float* __restrict__ Hin) {
  int bh = blockIdx.x >> 2, esp = blockIdx.x & 3;
  int e = esp*1024 + threadIdx.x*4;
  size_t base0 = (size_t)bh*NCH*4096 + e;
  float4 H = make_float4(0.f,0.f,0.f,0.f);
  float4 g = *(const float4*)(G + base0);
  float d = dec[bh*NCH];
  for (int c = 0; c < NCH; ++c) {
    float4 gn = make_float4(0.f,0.f,0.f,0.f); float dn = 0.f;
    if (c + 1 < NCH) {
      gn = *(const float4*)(G + base0 + (size_t)(c+1)*4096);
      dn = dec[bh*NCH + c + 1];
    }
    *(float4*)(Hin + base0 + (size_t)c*4096) = H;   // carry-in for chunk c
    H.x = H.x*d + g.x; H.y = H.y*d + g.y; H.z = H.z*d + g.z; H.w = H.w*d + g.w;
    g = gn; d = dn;
  }
}

// ---------------------------------------------------------------- phase C: chunk output
// All three 64^3 matmuls on bf16x3 MFMA; fp32 mask/scalars. (R15-verified.)
__global__ void __launch_bounds__(256) k_chunk_out(
    const float* __restrict__ zx, const float* __restrict__ xbc,
    const float* __restrict__ A_log, const float* __restrict__ Hin,
    float* __restrict__ y) {
  int blk = blockIdx.x;
  int c = blk & (NCH-1), hd = (blk >> 5) & 3, b = blk >> 7;
  int t0 = c*QC;
  int tid = threadIdx.x;
  int wv = tid >> 6, lane = tid & 63;
  int m = lane & 15, q = lane >> 4;
  float A = -__expf(A_log[hd]);
  __shared__ __align__(16) unsigned short CH[QC*LDS2], CL[QC*LDS2]; // C [t][n]
  __shared__ __align__(16) unsigned short BH[QC*LDS2], BL[QC*LDS2]; // B [s][n] -> M [t][s]
  __shared__ __align__(16) unsigned short TH[QC*LDS2], TL[QC*LDS2]; // HT [p][n] -> Xt [p][s]
  __shared__ float cum[QC], dts[QC], pref[QC];
  if (tid < 64) {
    int tg = t0 + tid;
    float dtv = (tg < LH) ? zx[((size_t)b*LH + tg)*DPROJ + 640 + hd] : 0.f;
    float s = dtv;
#pragma unroll
    for (int off = 1; off < 64; off <<= 1) {
      float u = __shfl_up(s, off);
      if (tid >= off) s += u;
    }
    dts[tid] = dtv; cum[tid] = s; pref[tid] = __expf(A*s);
  }
  for (int i = tid; i < 2048; i += 256) {
    int s = i >> 5, j2 = (i & 31)*2;
    int tg = t0 + s;
    float b0 = 0.f, b1 = 0.f, c0_ = 0.f, c1_ = 0.f;
    if (tg < LH) {
      size_t row = ((size_t)b*LH + tg)*CONVD;
      float2 bv = *(const float2*)(xbc + row + DIN + j2);
      float2 cv = *(const float2*)(xbc + row + DIN + NSTATE + j2);
      b0 = bv.x; b1 = bv.y; c0_ = cv.x; c1_ = cv.y;
    }
    int o = s*LDS2 + j2;
    *(unsigned int*)(BH + o) = pack2(b0, b1);
    *(unsigned int*)(BL + o) = pack2lo(b0, b1);
    *(unsigned int*)(CH + o) = pack2(c0_, c1_);
    *(unsigned int*)(CL + o) = pack2lo(c0_, c1_);
  }
  size_t hbase = (size_t)blk*4096;
  for (int i = tid; i < 2048; i += 256) {
    int p = i & 63, n2 = (i >> 6)*2;
    float v0 = Hin[hbase + (size_t)n2*64 + p];
    float v1 = Hin[hbase + (size_t)(n2+1)*64 + p];
    int o = p*LDS2 + n2;
    *(unsigned int*)(TH + o) = pack2(v0, v1);
    *(unsigned int*)(TL + o) = pack2lo(v0, v1);
  }
  __syncthreads();
  bf16x8 ch[2], cl[2];
#pragma unroll
  for (int kc = 0; kc < 2; ++kc) {
    int off = (wv*16 + m)*LDS2 + kc*32 + q*8;
    ch[kc] = ldfrag(CH, off);
    cl[kc] = ldfrag(CL, off);
  }
  f32x4 sacc[4], y2a[4];
#pragma unroll
  for (int nt = 0; nt < 4; ++nt) {
    f32x4 a1 = {0.f,0.f,0.f,0.f}, a2 = {0.f,0.f,0.f,0.f};
#pragma unroll
    for (int kc = 0; kc < 2; ++kc) {
      int off = (nt*16 + m)*LDS2 + kc*32 + q*8;
      bf16x8 bh = ldfrag(BH, off), bl = ldfrag(BL, off);
      bf16x8 th = ldfrag(TH, off), tl = ldfrag(TL, off);
      a1 = __builtin_amdgcn_mfma_f32_16x16x32_bf16(cl[kc], bh, a1, 0, 0, 0);
      a1 = __builtin_amdgcn_mfma_f32_16x16x32_bf16(ch[kc], bl, a1, 0, 0, 0);
      a1 = __builtin_amdgcn_mfma_f32_16x16x32_bf16(ch[kc], bh, a1, 0, 0, 0);
      a2 = __builtin_amdgcn_mfma_f32_16x16x32_bf16(cl[kc], th, a2, 0, 0, 0);
      a2 = __builtin_amdgcn_mfma_f32_16x16x32_bf16(ch[kc], tl, a2, 0, 0, 0);
      a2 = __builtin_amdgcn_mfma_f32_16x16x32_bf16(ch[kc], th, a2, 0, 0, 0);
    }
    sacc[nt] = a1; y2a[nt] = a2;
  }
  __syncthreads();   // all waves done reading BH/TH before overwrite
#pragma unroll
  for (int nt = 0; nt < 4; ++nt) {
    int s = nt*16 + m;
#pragma unroll
    for (int r = 0; r < 4; ++r) {
      int t = wv*16 + q*4 + r;
      float mv = 0.f;
      if (s <= t) mv = sacc[nt][r] * __expf(A*(cum[t] - cum[s])) * dts[s];
      unsigned short hi = f2bf(mv);
      BH[t*LDS2 + s] = hi;
      BL[t*LDS2 + s] = f2bf(mv - bf2f(hi));
    }
  }
  for (int i = tid; i < 2048; i += 256) {
    int p = i & 63, s2 = (i >> 6)*2;
    int tg = t0 + s2;
    float v0 = (tg < LH)   ? xbc[((size_t)b*LH + tg)*CONVD + hd*PDIM + p]   : 0.f;
    float v1 = (tg+1 < LH) ? xbc[((size_t)b*LH + tg+1)*CONVD + hd*PDIM + p] : 0.f;
    int o = p*LDS2 + s2;
    *(unsigned int*)(TH + o) = pack2(v0, v1);
    *(unsigned int*)(TL + o) = pack2lo(v0, v1);
  }
  __syncthreads();
  bf16x8 mh[2], ml[2];
#pragma unroll
  for (int kc = 0; kc < 2; ++kc) {
    int off = (wv*16 + m)*LDS2 + kc*32 + q*8;
    mh[kc] = ldfrag(BH, off);
    ml[kc] = ldfrag(BL, off);
  }
#pragma unroll
  for (int nt = 0; nt < 4; ++nt) {
    f32x4 a1 = {0.f,0.f,0.f,0.f};
#pragma unroll
    for (int kc = 0; kc < 2; ++kc) {
      int off = (nt*16 + m)*LDS2 + kc*32 + q*8;
      bf16x8 th = ldfrag(TH, off), tl = ldfrag(TL, off);
      a1 = __builtin_amdgcn_mfma_f32_16x16x32_bf16(ml[kc], th, a1, 0, 0, 0);
      a1 = __builtin_amdgcn_mfma_f32_16x16x32_bf16(mh[kc], tl, a1, 0, 0, 0);
      a1 = __builtin_amdgcn_mfma_f32_16x16x32_bf16(mh[kc], th, a1, 0, 0, 0);
    }
    int p = nt*16 + m;
#pragma unroll
    for (int r = 0; r < 4; ++r) {
      int t = wv*16 + q*4 + r, tg = t0 + t;
      if (tg < LH)
        y[((size_t)b*LH + tg)*DIN + hd*PDIM + p] = a1[r] + pref[t]*y2a[nt][r];
    }
  }
}

// ---------------------------------------------------------------- gate+rmsnorm+out_proj
// FUSED with next layer's in_proj. 32 tokens/block (grid 512) — halves the
// per-layer in_proj weight L2 stream vs 16-token blocks (R17: 688 MB -> 344 MB).
__global__ void __launch_bounds__(256) k_out_fused(
    const float* __restrict__ y, const float* __restrict__ xbc,
    float* __restrict__ zx, const float* __restrict__ Dh,
    const float* __restrict__ nw, const unsigned short* __restrict__ oH,
    const unsigned short* __restrict__ oL,
    const unsigned short* __restrict__ wH, const unsigned short* __restrict__ wL,
    const float* __restrict__ dtb, float* __restrict__ hout, int doProj) {
  int b = blockIdx.x >> 6;
  int l0 = (blockIdx.x & 63) * 32;
  int t = threadIdx.x;
  __shared__ __align__(16) unsigned short yH[32*LDSY], yL[32*LDSY];   // 33.8 KB
  __shared__ __align__(16) unsigned short hsH[32*LDSH], hsL[32*LDSH]; // 17.4 KB
  __shared__ float red[16][4];
  __shared__ float rs[16];
  int c = t;
  int hd = c >> 6;
  float dcoef = Dh[hd];
  float nwc = nw[c];
  int wave = t >> 6, lane = t & 63;
  // ---- phase 1: gate + RMSnorm, two 16-row passes
  for (int hf = 0; hf < 2; ++hf) {
    float v[16];
#pragma unroll
    for (int r = 0; r < 16; ++r) {
      int l = l0 + hf*16 + r;
      float val = 0.f;
      if (l < LH) {
        size_t row = (size_t)b*LH + l;
        float ys = y[row*DIN + c];
        float xh = xbc[row*CONVD + c];
        float z  = zx[row*DPROJ + c];
        val = (ys + dcoef*xh) * siluf_(z);
      }
      v[r] = val;
    }
#pragma unroll
    for (int r = 0; r < 16; ++r) {
      float sq = v[r]*v[r];
      for (int off = 32; off > 0; off >>= 1) sq += __shfl_down(sq, off);
      if (lane == 0) red[r][wave] = sq;
    }
    __syncthreads();
    if (t < 16) {
      float sm = red[t][0]+red[t][1]+red[t][2]+red[t][3];
      rs[t] = rsqrtf(sm/(float)DIN + 1e-5f);
    }
    __syncthreads();
#pragma unroll
    for (int r = 0; r < 16; ++r) {
      float val = v[r] * rs[r] * nwc;
      unsigned short hi = f2bf(val);
      yH[(hf*16 + r)*LDSY + c] = hi;
      yL[(hf*16 + r)*LDSY + c] = f2bf(val - bf2f(hi));
    }
    __syncthreads();
  }
  int m = lane & 15, q = lane >> 4;
  // ---- phase 2: out_proj (row-tile outer, resident A-frags, streamed oH/oL)
  for (int rt = 0; rt < 2; ++rt) {
    bf16x8 ah[8], al[8];
#pragma unroll
    for (int kb = 0; kb < 8; ++kb) {
      int off = (rt*16 + m)*LDSY + kb*32 + q*8;
      ah[kb] = ldfrag(yH, off);
      al[kb] = ldfrag(yL, off);
    }
#pragma unroll
    for (int jtp = 0; jtp < 2; ++jtp) {
      int jt = wave + jtp*4;                // waves cover jt 0..7
      f32x4 acc = {0.f,0.f,0.f,0.f};
#pragma unroll
      for (int kb = 0; kb < 8; ++kb) {
        size_t woff = (((size_t)jt*8 + kb)*64 + lane)*8;   // coalesced
        bf16x8 bh = *(const bf16x8*)(oH + woff);
        bf16x8 bl = *(const bf16x8*)(oL + woff);
        acc = __builtin_amdgcn_mfma_f32_16x16x32_bf16(al[kb], bh, acc, 0, 0, 0);
        acc = __builtin_amdgcn_mfma_f32_16x16x32_bf16(ah[kb], bl, acc, 0, 0, 0);
        acc = __builtin_amdgcn_mfma_f32_16x16x32_bf16(ah[kb], bh, acc, 0, 0, 0);
      }
      int j = jt*16 + m;                    // D col = lane&15
#pragma unroll
      for (int r = 0; r < 4; ++r) {
        int rr = rt*16 + q*4 + r;           // D row = token-in-block
        float val = acc[r];
        unsigned short hi = f2bf(val);
        hsH[rr*LDSH + j] = hi;
        hsL[rr*LDSH + j] = f2bf(val - bf2f(hi));
        int l = l0 + rr;
        if (!doProj && l < LH) hout[((size_t)b*LH + l)*DIM + j] = val;
      }
    }
  }
  if (!doProj) return;
  __syncthreads();
  // ---- phase 3: in_proj of next layer. Both row-tiles' A-frags resident so
  // each j-tile's weights are loaded once and feed 24 MFMA.
  bf16x8 ah0[4], al0[4], ah1[4], al1[4];
#pragma unroll
  for (int kb = 0; kb < 4; ++kb) {
    int off0 = m*LDSH + kb*32 + q*8;
    int off1 = (16 + m)*LDSH + kb*32 + q*8;
    ah0[kb] = ldfrag(hsH, off0); al0[kb] = ldfrag(hsL, off0);
    ah1[kb] = ldfrag(hsH, off1); al1[kb] = ldfrag(hsL, off1);
  }
#pragma unroll 1
  for (int jt = wave; jt < NJT; jt += 4) {
    size_t woff = (((size_t)jt*4)*64 + lane)*8;
    bf16x8 bh[4], bl[4];
#pragma unroll
    for (int kb = 0; kb < 4; ++kb) {
      bh[kb] = *(const bf16x8*)(wH + woff + (size_t)kb*64*8);  // coalesced
      bl[kb] = *(const bf16x8*)(wL + woff + (size_t)kb*64*8);
    }
    f32x4 a0 = {0.f,0.f,0.f,0.f}, a1 = {0.f,0.f,0.f,0.f};
#pragma unroll
    for (int kb = 0; kb < 4; ++kb) {
      a0 = __builtin_amdgcn_mfma_f32_16x16x32_bf16(al0[kb], bh[kb], a0, 0, 0, 0);
      a0 = __builtin_amdgcn_mfma_f32_16x16x32_bf16(ah0[kb], bl[kb], a0, 0, 0, 0);
      a0 = __builtin_amdgcn_mfma_f32_16x16x32_bf16(ah0[kb], bh[kb], a0, 0, 0, 0);
      a1 = __builtin_amdgcn_mfma_f32_16x16x32_bf16(al1[kb], bh[kb], a1, 0, 0, 0);
      a1 = __builtin_amdgcn_mfma_f32_16x16x32_bf16(ah1[kb], bl[kb], a1, 0, 0, 0);
      a1 = __builtin_amdgcn_mfma_f32_16x16x32_bf16(ah1[kb], bh[kb], a1, 0, 0, 0);
    }
    int jj = jt*16 + m;
    if (jj < DPROJ) {
      bool isdt = (jj >= 640);
      float bias = isdt ? dtb[jj - 640] : 0.f;
#pragma unroll
      for (int r = 0; r < 4; ++r) {
        int tok0 = l0 + q*4 + r;
        int tok1 = l0 + 16 + q*4 + r;
        if (tok0 < LH) {
          float vv = a0[r];
          if (isdt) { vv += bias; vv = (vv > 20.f) ? vv : log1pf(__expf(vv)); }
          zx[((size_t)b*LH + tok0)*DPROJ + jj] = vv;
        }
        if (tok1 < LH) {
          float vv = a1[r];
          if (isdt) { vv += bias; vv = (vv > 20.f) ? vv : log1pf(__expf(vv)); }
          zx[((size_t)b*LH + tok1)*DPROJ + jj] = vv;
        }
      }
    }
  }
}

// ---------------------------------------------------------------- final LN + head
__global__ void k_head(const float* __restrict__ h, const float* __restrict__ lnw,
                       const float* __restrict__ lnb, const float* __restrict__ hw,
                       const float* __restrict__ hb, float* __restrict__ out) {
  int b = blockIdx.x; int t = threadIdx.x;
  __shared__ float red[2];
  int wave = t >> 6, lane = t & 63;
  float v = h[((size_t)b*LH + LSEQ)*DIM + t];
  float s = v;
  for (int off = 32; off > 0; off >>= 1) s += __shfl_down(s, off);
  if (lane == 0) red[wave] = s;
  __syncthreads();
  float mean = (red[0]+red[1]) / (float)DIM;
  __syncthreads();
  float d = v - mean; float sq = d*d;
  for (int off = 32; off > 0; off >>= 1) sq += __shfl_down(sq, off);
  if (lane == 0) red[wave] = sq;
  __syncthreads();
  float var = (red[0]+red[1]) / (float)DIM;
  float cn = d*rsqrtf(var + 1e-5f)*lnw[t] + lnb[t];
  float dot = cn*hw[t];
  __syncthreads();
  for (int off = 32; off > 0; off >>= 1) dot += __shfl_down(dot, off);
  if (lane == 0) red[wave] = dot;
  __syncthreads();
  if (t == 0) out[b] = red[0]+red[1] + hb[0];
}

extern "C" void kernel_launch(void* const* d_in, const int* in_sizes, int n_in,
                              void* d_out, int out_size, void* d_ws, size_t ws_size,
                              hipStream_t stream) {
  const float* x     = (const float*)d_in[0];
  const float* w1    = (const float*)d_in[1];
  const float* b1    = (const float*)d_in[2];
  const float* w2    = (const float*)d_in[3];
  const float* b2    = (const float*)d_in[4];
  const float* cls   = (const float*)d_in[5];
  const float* inw   = (const float*)d_in[6];   // (4, 644, 128)
  const float* cw    = (const float*)d_in[7];   // (4, 384, 4)
  const float* cb    = (const float*)d_in[8];   // (4, 384)
  const float* dtb   = (const float*)d_in[9];   // (4, 4)
  const float* Alog  = (const float*)d_in[10];  // (4, 4)
  const float* Dh    = (const float*)d_in[11];  // (4, 4)
  const float* nw    = (const float*)d_in[12];  // (4, 256)
  const float* ow    = (const float*)d_in[13];  // (4, 128, 256)
  const float* lnw   = (const float*)d_in[14];
  const float* lnb   = (const float*)d_in[15];
  const float* hw    = (const float*)d_in[16];
  const float* hb    = (const float*)d_in[17];

  float* ws   = (float*)d_ws;
  float* zx   = ws;                                   // 10,535,840
  float* xbc  = zx + (size_t)BATCH*LH*DPROJ;          // 6,282,240
  float* ybuf = xbc + (size_t)BATCH*LH*CONVD;         // 4,194,304 (G aliases ybuf)
  float* G    = ybuf;
  float* Hin  = ybuf + 4194304;                       // 4,194,304
  float* dec  = Hin  + 4194304;                       // 1,024
  unsigned short* hH = (unsigned short*)(dec + 1024);      // 8*2048*128 u16
  unsigned short* hL = hH + (size_t)BATCH*LHP*DIM;         // 8*2048*128 u16
  unsigned short* wH = hL + (size_t)BATCH*LHP*DIM;         // 4*41*4*64*8 u16
  unsigned short* wL = wH + (size_t)DEPTH*NJT*4*64*8;      // same
  unsigned short* oH = wL + (size_t)DEPTH*NJT*4*64*8;      // 4*8*8*64*8 u16
  unsigned short* oL = oH + (size_t)DEPTH*8*8*64*8;        // same
  // total ~27.8M floats-equivalent = ~111 MiB

  float* hout = (float*)d_out + 8;   // final h written directly into output

  k_cast_w<<<(DEPTH*NJT*4*64 + 255)/256, 256, 0, stream>>>(inw, wH, wL);
  k_cast_ow<<<(DEPTH*8*8*64 + 255)/256, 256, 0, stream>>>(ow, oH, oL);

  k_front<<<BATCH*64 + 1, 256, 0, stream>>>(x, w1, b1, w2, b2, cls, hH, hL);
  k_inproj_mfma<<<BATCH*64, 256, 0, stream>>>(hH, hL, wH, wL, dtb, zx);

  for (int i = 0; i < DEPTH; ++i) {
    int doProj = (i < DEPTH-1) ? 1 : 0;
    int nxt = doProj ? (i+1) : 0;
    k_conv<<<(int)(((long)BATCH*LH*(CONVD/4) + 255)/256), 256, 0, stream>>>(
        zx, cw + (size_t)i*CONVD*4, cb + (size_t)i*CONVD, xbc);
    k_chunk_state<<<BATCH*NH*NCH, 256, 0, stream>>>(zx, xbc, Alog + i*NH, G, dec);
    k_combine<<<BATCH*NH*4, 256, 0, stream>>>(G, dec, Hin);
    k_chunk_out<<<BATCH*NH*NCH, 256, 0, stream>>>(zx, xbc, Alog + i*NH, Hin, ybuf);
    k_out_fused<<<BATCH*64, 256, 0, stream>>>(
        ybuf, xbc, zx, Dh + i*NH, nw + (size_t)i*DIN,
        oH + (size_t)i*8*8*64*8, oL + (size_t)i*8*8*64*8,
        wH + (size_t)nxt*NJT*4*64*8, wL + (size_t)nxt*NJT*4*64*8,
        dtb + nxt*NH, hout, doProj);
  }

  k_head<<<BATCH, 128, 0, stream>>>(hout, lnw, lnb, hw, hb, (float*)d_out);
}

// Round 19
// 564.119 us; speedup vs baseline: 1.0465x; 1.0465x over previous
//
#include <hip/hip_runtime.h>
#include <math.h>

// Shapes (fixed by setup_inputs)
#define BATCH 8
#define TSEQ 2048
#define CIN 3
#define WIN 5
#define LSEQ 2044          // T - WIN + 1
#define LH 2045            // LSEQ + 1 (cls token appended)
#define LHP 2048           // padded token rows for bf16 h buffers
#define DIM 128
#define DEPTH 4
#define DIN 256            // d_inner
#define NH 4               // heads
#define PDIM 64            // headdim
#define NSTATE 64          // d_state
#define CONVD 384          // d_inner + 2*d_state
#define DPROJ 644          // 2*d_inner + 2*d_state + nheads
#define NJT 41             // j-tiles of 16 (41*16 = 656 >= 644)
#define QC 64              // chunk length
#define NCH 32             // number of chunks
#define LDS2 68            // padded LDS row stride (shorts, 64-col frag buffers)
#define LDSY 268           // padded stride (shorts): 134 dwords ≡ 6 mod 32 -> frag reads bank-free
#define LDSH 140           // padded stride (shorts): 70 dwords ≡ 6 mod 32 -> bank-free, 8B-aligned rows
#define FTR 32             // tokens per k_front block

typedef __attribute__((ext_vector_type(8))) short bf16x8;
typedef __attribute__((ext_vector_type(4))) float f32x4;
union Frag8 { bf16x8 v; uint2 u[2]; };

__device__ __forceinline__ float sigmoidf_(float x){ return 1.f/(1.f+__expf(-x)); }
__device__ __forceinline__ float siluf_(float x){ return x*sigmoidf_(x); }
__device__ __forceinline__ unsigned short f2bf(float f){   // RNE fp32->bf16
  unsigned int u = __float_as_uint(f);
  return (unsigned short)((u + 0x7FFFu + ((u >> 16) & 1u)) >> 16);
}
__device__ __forceinline__ float bf2f(unsigned short u){
  return __uint_as_float(((unsigned int)u) << 16);
}
__device__ __forceinline__ unsigned int pack2(float a, float b){  // [lo addr]=a
  return (unsigned int)f2bf(a) | ((unsigned int)f2bf(b) << 16);
}
__device__ __forceinline__ unsigned int pack2lo(float a, float b){
  float ra = a - bf2f(f2bf(a)), rb = b - bf2f(f2bf(b));
  return (unsigned int)f2bf(ra) | ((unsigned int)f2bf(rb) << 16);
}
__device__ __forceinline__ bf16x8 ldfrag(const unsigned short* base, int off){
  Frag8 f;
  f.u[0] = *(const uint2*)(base + off);
  f.u[1] = *(const uint2*)(base + off + 4);
  return f.v;
}

// inw -> MFMA-fragment-order bf16 hi/lo: wS[layer][jt][kb][lane][8].
__global__ void __launch_bounds__(256) k_cast_w(
    const float* __restrict__ w, unsigned short* __restrict__ wH,
    unsigned short* __restrict__ wL) {
  int gid = blockIdx.x*256 + threadIdx.x;     // [ly][jt][kb][lane]
  if (gid >= DEPTH*NJT*4*64) return;
  int lane = gid & 63;
  int kb = (gid >> 6) & 3;
  int jt = (gid >> 8) % NJT;
  int ly = gid / (NJT*4*64);
  int m = lane & 15, q = lane >> 4;
  int j = jt*16 + m;
  int k = kb*32 + q*8;
  unsigned short hi[8], lo[8];
  if (j < DPROJ) {
    const float* src = w + ((size_t)ly*DPROJ + j)*DIM + k;
#pragma unroll
    for (int i = 0; i < 8; ++i) {
      float v = src[i];
      hi[i] = f2bf(v);
      lo[i] = f2bf(v - bf2f(hi[i]));
    }
  } else {
#pragma unroll
    for (int i = 0; i < 8; ++i) { hi[i] = 0; lo[i] = 0; }
  }
  size_t dst = (size_t)gid*8;
  *(uint4*)(wH + dst) = *(const uint4*)hi;
  *(uint4*)(wL + dst) = *(const uint4*)lo;
}

// ow (4,128,256) -> fragment-order bf16 hi/lo: oS[layer][jt(8)][kb(8)][lane][8].
__global__ void __launch_bounds__(256) k_cast_ow(
    const float* __restrict__ ow, unsigned short* __restrict__ oH,
    unsigned short* __restrict__ oL) {
  int gid = blockIdx.x*256 + threadIdx.x;
  if (gid >= DEPTH*8*8*64) return;
  int lane = gid & 63;
  int kb = (gid >> 6) & 7;
  int jt = (gid >> 9) & 7;
  int ly = gid >> 12;
  int m = lane & 15, q = lane >> 4;
  int j = jt*16 + m;
  int k = kb*32 + q*8;
  const float* src = ow + ((size_t)ly*DIM + j)*DIN + k;
  unsigned short hi[8], lo[8];
#pragma unroll
  for (int i = 0; i < 8; ++i) {
    float v = src[i];
    hi[i] = f2bf(v);
    lo[i] = f2bf(v - bf2f(hi[i]));
  }
  size_t dst = (size_t)gid*8;
  *(uint4*)(oH + dst) = *(const uint4*)hi;
  *(uint4*)(oL + dst) = *(const uint4*)lo;
}

// ---------------------------------------------------------------- front MLP (writes hi/lo only)
__global__ void __launch_bounds__(256) k_front(
    const float* __restrict__ x, const float* __restrict__ w1,
    const float* __restrict__ b1, const float* __restrict__ w2,
    const float* __restrict__ b2, const float* __restrict__ cls,
    unsigned short* __restrict__ hH, unsigned short* __restrict__ hL) {
  int t = threadIdx.x;
  if (blockIdx.x == BATCH*64) {              // cls rows
    if (t < DIM) {
      float cv = cls[t];
      unsigned short hi = f2bf(cv);
      unsigned short lo = f2bf(cv - bf2f(hi));
      for (int b = 0; b < BATCH; ++b) {
        hH[((size_t)b*LHP + LSEQ)*DIM + t] = hi;
        hL[((size_t)b*LHP + LSEQ)*DIM + t] = lo;
      }
    }
    return;
  }
  int b = blockIdx.x >> 6;
  int c0 = (blockIdx.x & 63) * FTR;
  __shared__ float xs[(FTR+4)*CIN];
  __shared__ float w1s[DIM*17];
  __shared__ __align__(16) float h1s[FTR][DIM];
  __shared__ float part[FTR][DIM][2];
  for (int i = t; i < (FTR+4)*CIN; i += 256) {
    int row = c0 + i/3, ch = i - (i/3)*3;
    xs[i] = (row < TSEQ) ? x[(size_t)b*TSEQ*CIN + (size_t)row*CIN + ch] : 0.f;
  }
  for (int i = t; i < DIM*15; i += 256) {
    int j = i/15, k = i - j*15;
    w1s[j*17+k] = w1[i];
  }
  __syncthreads();
  {
    int j = t & 127, rh = t >> 7;
    float bias = b1[j];
    const float* wr = &w1s[j*17];
    for (int r = rh*16; r < rh*16+16; ++r) {
      float a = bias;
#pragma unroll
      for (int k = 0; k < 15; ++k) a += xs[r*3+k]*wr[k];
      h1s[r][j] = 0.5f*a*(1.f + erff(a*0.70710678118654752f));  // exact gelu
    }
  }
  __syncthreads();
  {
    int j = t & 127, hf = t >> 7;
    float4 wv[16];
    const float4* w2r = (const float4*)(w2 + (size_t)j*DIM + hf*64);
#pragma unroll
    for (int k4 = 0; k4 < 16; ++k4) wv[k4] = w2r[k4];
#pragma unroll 2
    for (int r = 0; r < FTR; ++r) {
      const float4* hr = (const float4*)&h1s[r][hf*64];
      float acc = 0.f;
#pragma unroll
      for (int k4 = 0; k4 < 16; ++k4) {
        float4 hv = hr[k4];
        acc += wv[k4].x*hv.x + wv[k4].y*hv.y + wv[k4].z*hv.z + wv[k4].w*hv.w;
      }
      part[r][j][hf] = acc;
    }
  }
  __syncthreads();
  if (t < DIM) {
    float bias = b2[t];
    for (int r = 0; r < FTR; ++r) {
      int l = c0 + r;
      if (l < LSEQ) {
        float val = part[r][t][0] + part[r][t][1] + bias;
        unsigned short hi = f2bf(val);
        hH[((size_t)b*LHP + l)*DIM + t] = hi;
        hL[((size_t)b*LHP + l)*DIM + t] = f2bf(val - bf2f(hi));
      }
    }
  }
}

// ---------------------------------------------------------------- in_proj via bf16x3 MFMA
// (layer 0 only — layers 1..3 are fused into k_out_fused)
__global__ void __launch_bounds__(256) k_inproj_mfma(
    const unsigned short* __restrict__ hH, const unsigned short* __restrict__ hL,
    const unsigned short* __restrict__ wH, const unsigned short* __restrict__ wL,
    const float* __restrict__ dtb, float* __restrict__ zx) {
  int b = blockIdx.x >> 6;
  int r = blockIdx.x & 63;
  int lb = r >> 1, jh = r & 1;
  int wv = threadIdx.x >> 6, lane = threadIdx.x & 63;
  int l0 = lb*64 + wv*16;
  int m = lane & 15, q = lane >> 4;
  size_t hoff = ((size_t)b*LHP + (l0 + m))*DIM + q*8;
  bf16x8 ah[4], al[4];
#pragma unroll
  for (int kb = 0; kb < 4; ++kb) {
    ah[kb] = *(const bf16x8*)(hH + hoff + kb*32);
    al[kb] = *(const bf16x8*)(hL + hoff + kb*32);
  }
  int jt0 = jh ? 21 : 0, jtn = jh ? NJT : 21;
#pragma unroll 2
  for (int jt = jt0; jt < jtn; ++jt) {
    size_t woff = (((size_t)jt*4)*64 + lane)*8;
    bf16x8 bh[4], bl[4];
#pragma unroll
    for (int kb = 0; kb < 4; ++kb) {
      bh[kb] = *(const bf16x8*)(wH + woff + (size_t)kb*64*8);  // coalesced
      bl[kb] = *(const bf16x8*)(wL + woff + (size_t)kb*64*8);
    }
    f32x4 acc = {0.f, 0.f, 0.f, 0.f};
#pragma unroll
    for (int kb = 0; kb < 4; ++kb)
      acc = __builtin_amdgcn_mfma_f32_16x16x32_bf16(al[kb], bh[kb], acc, 0, 0, 0);
#pragma unroll
    for (int kb = 0; kb < 4; ++kb)
      acc = __builtin_amdgcn_mfma_f32_16x16x32_bf16(ah[kb], bl[kb], acc, 0, 0, 0);
#pragma unroll
    for (int kb = 0; kb < 4; ++kb)
      acc = __builtin_amdgcn_mfma_f32_16x16x32_bf16(ah[kb], bh[kb], acc, 0, 0, 0);
    int jj = jt*16 + m;                     // D col = lane&15
    if (jj < DPROJ) {
      bool isdt = (jj >= 640);
      float bias = isdt ? dtb[jj - 640] : 0.f;
#pragma unroll
      for (int rr = 0; rr < 4; ++rr) {
        int tok = l0 + q*4 + rr;            // D row = q*4 + reg
        if (tok < LH) {
          float v = acc[rr];
          if (isdt) { v += bias; v = (v > 20.f) ? v : log1pf(__expf(v)); }
          zx[((size_t)b*LH + tok)*DPROJ + jj] = v;
        }
      }
    }
  }
}

// ---------------------------------------------------------------- causal dwconv + silu
__global__ void k_conv(const float* __restrict__ zx, const float* __restrict__ cw,
                       const float* __restrict__ cb, float* __restrict__ xbc) {
  size_t idx = (size_t)blockIdx.x*blockDim.x + threadIdx.x;
  const size_t total = (size_t)BATCH*LH*(CONVD/4);
  if (idx >= total) return;
  int c4 = (int)(idx % (CONVD/4)) * 4;
  size_t bl = idx / (CONVD/4);
  int l = (int)(bl % LH); int b = (int)(bl / LH);
  float4 w0 = *(const float4*)(cw + (c4+0)*4);
  float4 w1 = *(const float4*)(cw + (c4+1)*4);
  float4 w2 = *(const float4*)(cw + (c4+2)*4);
  float4 w3 = *(const float4*)(cw + (c4+3)*4);
  float4 a = *(const float4*)(cb + c4);
#pragma unroll
  for (int k = 0; k < 4; ++k) {
    int tin = l - 3 + k;
    if (tin >= 0) {
      float4 v = *(const float4*)(zx + ((size_t)b*LH + tin)*DPROJ + DIN + c4);
      a.x += v.x * ((const float*)&w0)[k];
      a.y += v.y * ((const float*)&w1)[k];
      a.z += v.z * ((const float*)&w2)[k];
      a.w += v.w * ((const float*)&w3)[k];
    }
  }
  float4 o;
  o.x = siluf_(a.x); o.y = siluf_(a.y); o.z = siluf_(a.z); o.w = siluf_(a.w);
  *(float4*)(xbc + ((size_t)b*LH + l)*CONVD + c4) = o;
}

// ---------------------------------------------------------------- chunked SSD, phase A
// G[n][p] = sum_s (coef_s*B_s[n]) * X_s[p]  via bf16x3 MFMA. (R16-verified.)
__global__ void __launch_bounds__(256) k_chunk_state(
    const float* __restrict__ zx, const float* __restrict__ xbc,
    const float* __restrict__ A_log, float* __restrict__ G, float* __restrict__ dec) {
  int blk = blockIdx.x;
  int c = blk & (NCH-1), hd = (blk >> 5) & 3, b = blk >> 7;
  int t0 = c*QC;
  int tid = threadIdx.x;
  int wv = tid >> 6, lane = tid & 63;
  int m = lane & 15, q = lane >> 4;
  float A = -__expf(A_log[hd]);
  __shared__ __align__(16) unsigned short BcH[QC*LDS2], BcL[QC*LDS2]; // [n][s]
  __shared__ __align__(16) unsigned short XtH[QC*LDS2], XtL[QC*LDS2]; // [p][s]
  __shared__ float coef[QC];
  if (tid < 64) {
    int tg = t0 + tid;
    float dtv = (tg < LH) ? zx[((size_t)b*LH + tg)*DPROJ + 640 + hd] : 0.f;
    float s = dtv;
#pragma unroll
    for (int off = 1; off < 64; off <<= 1) {
      float u = __shfl_up(s, off);
      if (tid >= off) s += u;
    }
    float cq = __shfl(s, 63);
    coef[tid] = __expf(A*(cq - s)) * dtv;
    if (tid == 63) dec[blk] = __expf(A * s);
  }
  __syncthreads();
  for (int i = tid; i < 2048; i += 256) {
    int n = i & 63, s2 = (i >> 6)*2;
    int tg0 = t0 + s2, tg1 = t0 + s2 + 1;
    float b0 = 0.f, b1 = 0.f, x0 = 0.f, x1 = 0.f;
    if (tg0 < LH) {
      size_t row = ((size_t)b*LH + tg0)*CONVD;
      b0 = xbc[row + DIN + n] * coef[s2];
      x0 = xbc[row + hd*PDIM + n];
    }
    if (tg1 < LH) {
      size_t row = ((size_t)b*LH + tg1)*CONVD;
      b1 = xbc[row + DIN + n] * coef[s2+1];
      x1 = xbc[row + hd*PDIM + n];
    }
    int o = n*LDS2 + s2;
    *(unsigned int*)(BcH + o) = pack2(b0, b1);
    *(unsigned int*)(BcL + o) = pack2lo(b0, b1);
    *(unsigned int*)(XtH + o) = pack2(x0, x1);
    *(unsigned int*)(XtL + o) = pack2lo(x0, x1);
  }
  __syncthreads();
  bf16x8 ah[2], al[2];
#pragma unroll
  for (int kc = 0; kc < 2; ++kc) {
    int off = (wv*16 + m)*LDS2 + kc*32 + q*8;
    ah[kc] = ldfrag(BcH, off);
    al[kc] = ldfrag(BcL, off);
  }
#pragma unroll
  for (int nt = 0; nt < 4; ++nt) {
    f32x4 acc = {0.f,0.f,0.f,0.f};
#pragma unroll
    for (int kc = 0; kc < 2; ++kc) {
      int off = (nt*16 + m)*LDS2 + kc*32 + q*8;
      bf16x8 xh = ldfrag(XtH, off), xl = ldfrag(XtL, off);
      acc = __builtin_amdgcn_mfma_f32_16x16x32_bf16(al[kc], xh, acc, 0, 0, 0);
      acc = __builtin_amdgcn_mfma_f32_16x16x32_bf16(ah[kc], xl, acc, 0, 0, 0);
      acc = __builtin_amdgcn_mfma_f32_16x16x32_bf16(ah[kc], xh, acc, 0, 0, 0);
    }
    int p = nt*16 + m;
#pragma unroll
    for (int r = 0; r < 4; ++r) {
      int n = wv*16 + q*4 + r;
      G[(size_t)blk*4096 + n*64 + p] = acc[r];
    }
  }
}

// ---------------------------------------------------------------- phase B: inter-chunk
__global__ void __launch_bounds__(256) k_combine(
    const float* __restrict__ G, const float* __restrict__ dec, float* __restrict__ Hin) {
  int bh = blockIdx.x >> 2, esp = blockIdx.x & 3;
  int e = esp*1024 + threadIdx.x*4;
  size_t base0 = (size_t)bh*NCH*4096 + e;
  float4 H = make_float4(0.f,0.f,0.f,0.f);
  float4 g = *(const float4*)(G + base0);
  float d = dec[bh*NCH];
  for (int c = 0; c < NCH; ++c) {
    float4 gn = make_float4(0.f,0.f,0.f,0.f); float dn = 0.f;
    if (c + 1 < NCH) {
      gn = *(const float4*)(G + base0 + (size_t)(c+1)*4096);
      dn = dec[bh*NCH + c + 1];
    }
    *(float4*)(Hin + base0 + (size_t)c*4096) = H;   // carry-in for chunk c
    H.x = H.x*d + g.x; H.y = H.y*d + g.y; H.z = H.z*d + g.z; H.w = H.w*d + g.w;
    g = gn; d = dn;
  }
}

// ---------------------------------------------------------------- phase C: chunk output
// All three 64^3 matmuls on bf16x3 MFMA; fp32 mask/scalars. (R15-verified.)
__global__ void __launch_bounds__(256) k_chunk_out(
    const float* __restrict__ zx, const float* __restrict__ xbc,
    const float* __restrict__ A_log, const float* __restrict__ Hin,
    float* __restrict__ y) {
  int blk = blockIdx.x;
  int c = blk & (NCH-1), hd = (blk >> 5) & 3, b = blk >> 7;
  int t0 = c*QC;
  int tid = threadIdx.x;
  int wv = tid >> 6, lane = tid & 63;
  int m = lane & 15, q = lane >> 4;
  float A = -__expf(A_log[hd]);
  __shared__ __align__(16) unsigned short CH[QC*LDS2], CL[QC*LDS2]; // C [t][n]
  __shared__ __align__(16) unsigned short BH[QC*LDS2], BL[QC*LDS2]; // B [s][n] -> M [t][s]
  __shared__ __align__(16) unsigned short TH[QC*LDS2], TL[QC*LDS2]; // HT [p][n] -> Xt [p][s]
  __shared__ float cum[QC], dts[QC], pref[QC];
  if (tid < 64) {
    int tg = t0 + tid;
    float dtv = (tg < LH) ? zx[((size_t)b*LH + tg)*DPROJ + 640 + hd] : 0.f;
    float s = dtv;
#pragma unroll
    for (int off = 1; off < 64; off <<= 1) {
      float u = __shfl_up(s, off);
      if (tid >= off) s += u;
    }
    dts[tid] = dtv; cum[tid] = s; pref[tid] = __expf(A*s);
  }
  for (int i = tid; i < 2048; i += 256) {
    int s = i >> 5, j2 = (i & 31)*2;
    int tg = t0 + s;
    float b0 = 0.f, b1 = 0.f, c0_ = 0.f, c1_ = 0.f;
    if (tg < LH) {
      size_t row = ((size_t)b*LH + tg)*CONVD;
      float2 bv = *(const float2*)(xbc + row + DIN + j2);
      float2 cv = *(const float2*)(xbc + row + DIN + NSTATE + j2);
      b0 = bv.x; b1 = bv.y; c0_ = cv.x; c1_ = cv.y;
    }
    int o = s*LDS2 + j2;
    *(unsigned int*)(BH + o) = pack2(b0, b1);
    *(unsigned int*)(BL + o) = pack2lo(b0, b1);
    *(unsigned int*)(CH + o) = pack2(c0_, c1_);
    *(unsigned int*)(CL + o) = pack2lo(c0_, c1_);
  }
  size_t hbase = (size_t)blk*4096;
  for (int i = tid; i < 2048; i += 256) {
    int p = i & 63, n2 = (i >> 6)*2;
    float v0 = Hin[hbase + (size_t)n2*64 + p];
    float v1 = Hin[hbase + (size_t)(n2+1)*64 + p];
    int o = p*LDS2 + n2;
    *(unsigned int*)(TH + o) = pack2(v0, v1);
    *(unsigned int*)(TL + o) = pack2lo(v0, v1);
  }
  __syncthreads();
  bf16x8 ch[2], cl[2];
#pragma unroll
  for (int kc = 0; kc < 2; ++kc) {
    int off = (wv*16 + m)*LDS2 + kc*32 + q*8;
    ch[kc] = ldfrag(CH, off);
    cl[kc] = ldfrag(CL, off);
  }
  f32x4 sacc[4], y2a[4];
#pragma unroll
  for (int nt = 0; nt < 4; ++nt) {
    f32x4 a1 = {0.f,0.f,0.f,0.f}, a2 = {0.f,0.f,0.f,0.f};
#pragma unroll
    for (int kc = 0; kc < 2; ++kc) {
      int off = (nt*16 + m)*LDS2 + kc*32 + q*8;
      bf16x8 bh = ldfrag(BH, off), bl = ldfrag(BL, off);
      bf16x8 th = ldfrag(TH, off), tl = ldfrag(TL, off);
      a1 = __builtin_amdgcn_mfma_f32_16x16x32_bf16(cl[kc], bh, a1, 0, 0, 0);
      a1 = __builtin_amdgcn_mfma_f32_16x16x32_bf16(ch[kc], bl, a1, 0, 0, 0);
      a1 = __builtin_amdgcn_mfma_f32_16x16x32_bf16(ch[kc], bh, a1, 0, 0, 0);
      a2 = __builtin_amdgcn_mfma_f32_16x16x32_bf16(cl[kc], th, a2, 0, 0, 0);
      a2 = __builtin_amdgcn_mfma_f32_16x16x32_bf16(ch[kc], tl, a2, 0, 0, 0);
      a2 = __builtin_amdgcn_mfma_f32_16x16x32_bf16(ch[kc], th, a2, 0, 0, 0);
    }
    sacc[nt] = a1; y2a[nt] = a2;
  }
  __syncthreads();   // all waves done reading BH/TH before overwrite
#pragma unroll
  for (int nt = 0; nt < 4; ++nt) {
    int s = nt*16 + m;
#pragma unroll
    for (int r = 0; r < 4; ++r) {
      int t = wv*16 + q*4 + r;
      float mv = 0.f;
      if (s <= t) mv = sacc[nt][r] * __expf(A*(cum[t] - cum[s])) * dts[s];
      unsigned short hi = f2bf(mv);
      BH[t*LDS2 + s] = hi;
      BL[t*LDS2 + s] = f2bf(mv - bf2f(hi));
    }
  }
  for (int i = tid; i < 2048; i += 256) {
    int p = i & 63, s2 = (i >> 6)*2;
    int tg = t0 + s2;
    float v0 = (tg < LH)   ? xbc[((size_t)b*LH + tg)*CONVD + hd*PDIM + p]   : 0.f;
    float v1 = (tg+1 < LH) ? xbc[((size_t)b*LH + tg+1)*CONVD + hd*PDIM + p] : 0.f;
    int o = p*LDS2 + s2;
    *(unsigned int*)(TH + o) = pack2(v0, v1);
    *(unsigned int*)(TL + o) = pack2lo(v0, v1);
  }
  __syncthreads();
  bf16x8 mh[2], ml[2];
#pragma unroll
  for (int kc = 0; kc < 2; ++kc) {
    int off = (wv*16 + m)*LDS2 + kc*32 + q*8;
    mh[kc] = ldfrag(BH, off);
    ml[kc] = ldfrag(BL, off);
  }
#pragma unroll
  for (int nt = 0; nt < 4; ++nt) {
    f32x4 a1 = {0.f,0.f,0.f,0.f};
#pragma unroll
    for (int kc = 0; kc < 2; ++kc) {
      int off = (nt*16 + m)*LDS2 + kc*32 + q*8;
      bf16x8 th = ldfrag(TH, off), tl = ldfrag(TL, off);
      a1 = __builtin_amdgcn_mfma_f32_16x16x32_bf16(ml[kc], th, a1, 0, 0, 0);
      a1 = __builtin_amdgcn_mfma_f32_16x16x32_bf16(mh[kc], tl, a1, 0, 0, 0);
      a1 = __builtin_amdgcn_mfma_f32_16x16x32_bf16(mh[kc], th, a1, 0, 0, 0);
    }
    int p = nt*16 + m;
#pragma unroll
    for (int r = 0; r < 4; ++r) {
      int t = wv*16 + q*4 + r, tg = t0 + t;
      if (tg < LH)
        y[((size_t)b*LH + tg)*DIN + hd*PDIM + p] = a1[r] + pref[t]*y2a[nt][r];
    }
  }
}

// ---------------------------------------------------------------- gate+rmsnorm+out_proj
// FUSED with next layer's in_proj (R17 16-token structure; R19: bank-spread
// strides LDSY=268/LDSH=140 kill the 8-way frag-read conflicts seen in R18).
__global__ void __launch_bounds__(256) k_out_fused(
    const float* __restrict__ y, const float* __restrict__ xbc,
    float* __restrict__ zx, const float* __restrict__ Dh,
    const float* __restrict__ nw, const unsigned short* __restrict__ oH,
    const unsigned short* __restrict__ oL,
    const unsigned short* __restrict__ wH, const unsigned short* __restrict__ wL,
    const float* __restrict__ dtb, float* __restrict__ hout, int doProj) {
  int b = blockIdx.x >> 7;
  int l0 = (blockIdx.x & 127) * 16;
  int t = threadIdx.x;
  __shared__ __align__(16) unsigned short yH[16*LDSY], yL[16*LDSY];
  __shared__ __align__(16) unsigned short hsH[16*LDSH], hsL[16*LDSH];
  __shared__ float red[16][4];
  __shared__ float rs[16];
  int c = t;
  int hd = c >> 6;
  float dcoef = Dh[hd];
  float nwc = nw[c];
  float v[16];
#pragma unroll
  for (int r = 0; r < 16; ++r) {
    int l = l0 + r;
    float val = 0.f;
    if (l < LH) {
      size_t row = (size_t)b*LH + l;
      float ys = y[row*DIN + c];
      float xh = xbc[row*CONVD + c];
      float z  = zx[row*DPROJ + c];
      val = (ys + dcoef*xh) * siluf_(z);
    }
    v[r] = val;
  }
  int wave = t >> 6, lane = t & 63;
#pragma unroll
  for (int r = 0; r < 16; ++r) {
    float sq = v[r]*v[r];
    for (int off = 32; off > 0; off >>= 1) sq += __shfl_down(sq, off);
    if (lane == 0) red[r][wave] = sq;
  }
  __syncthreads();
  if (t < 16) {
    float sm = red[t][0]+red[t][1]+red[t][2]+red[t][3];
    rs[t] = rsqrtf(sm/(float)DIN + 1e-5f);
  }
  __syncthreads();
#pragma unroll
  for (int r = 0; r < 16; ++r) {
    float val = v[r] * rs[r] * nwc;
    unsigned short hi = f2bf(val);
    yH[r*LDSY + c] = hi;
    yL[r*LDSY + c] = f2bf(val - bf2f(hi));
  }
  __syncthreads();
  int m = lane & 15, q = lane >> 4;
  {
    bf16x8 ah[8], al[8];
#pragma unroll
    for (int kb = 0; kb < 8; ++kb) {
      int off = m*LDSY + kb*32 + q*8;
      ah[kb] = ldfrag(yH, off);
      al[kb] = ldfrag(yL, off);
    }
#pragma unroll
    for (int jtp = 0; jtp < 2; ++jtp) {
      int jt = wave*2 + jtp;
      f32x4 acc = {0.f,0.f,0.f,0.f};
#pragma unroll
      for (int kb = 0; kb < 8; ++kb) {
        size_t woff = (((size_t)jt*8 + kb)*64 + lane)*8;   // coalesced
        bf16x8 bh = *(const bf16x8*)(oH + woff);
        bf16x8 bl = *(const bf16x8*)(oL + woff);
        acc = __builtin_amdgcn_mfma_f32_16x16x32_bf16(al[kb], bh, acc, 0, 0, 0);
        acc = __builtin_amdgcn_mfma_f32_16x16x32_bf16(ah[kb], bl, acc, 0, 0, 0);
        acc = __builtin_amdgcn_mfma_f32_16x16x32_bf16(ah[kb], bh, acc, 0, 0, 0);
      }
      int j = jt*16 + m;                    // D col = lane&15
#pragma unroll
      for (int r = 0; r < 4; ++r) {
        int rr = q*4 + r;                   // D row = token-in-block
        float val = acc[r];                 // invalid rows produce 0 naturally
        unsigned short hi = f2bf(val);
        hsH[rr*LDSH + j] = hi;
        hsL[rr*LDSH + j] = f2bf(val - bf2f(hi));
        int l = l0 + rr;
        if (!doProj && l < LH) hout[((size_t)b*LH + l)*DIM + j] = val;
      }
    }
  }
  if (!doProj) return;
  __syncthreads();
  // ---- in_proj of next layer from the LDS h tile
  bf16x8 ah[4], al[4];
#pragma unroll
  for (int kb = 0; kb < 4; ++kb) {
    int off = m*LDSH + kb*32 + q*8;
    ah[kb] = ldfrag(hsH, off);
    al[kb] = ldfrag(hsL, off);
  }
#pragma unroll 2
  for (int jt = wave; jt < NJT; jt += 4) {
    size_t woff = (((size_t)jt*4)*64 + lane)*8;
    bf16x8 bh[4], bl[4];
#pragma unroll
    for (int kb = 0; kb < 4; ++kb) {
      bh[kb] = *(const bf16x8*)(wH + woff + (size_t)kb*64*8);  // coalesced
      bl[kb] = *(const bf16x8*)(wL + woff + (size_t)kb*64*8);
    }
    f32x4 acc = {0.f, 0.f, 0.f, 0.f};
#pragma unroll
    for (int kb = 0; kb < 4; ++kb)
      acc = __builtin_amdgcn_mfma_f32_16x16x32_bf16(al[kb], bh[kb], acc, 0, 0, 0);
#pragma unroll
    for (int kb = 0; kb < 4; ++kb)
      acc = __builtin_amdgcn_mfma_f32_16x16x32_bf16(ah[kb], bl[kb], acc, 0, 0, 0);
#pragma unroll
    for (int kb = 0; kb < 4; ++kb)
      acc = __builtin_amdgcn_mfma_f32_16x16x32_bf16(ah[kb], bh[kb], acc, 0, 0, 0);
    int jj = jt*16 + m;
    if (jj < DPROJ) {
      bool isdt = (jj >= 640);
      float bias = isdt ? dtb[jj - 640] : 0.f;
#pragma unroll
      for (int r = 0; r < 4; ++r) {
        int tok = l0 + q*4 + r;
        if (tok < LH) {
          float vv = acc[r];
          if (isdt) { vv += bias; vv = (vv > 20.f) ? vv : log1pf(__expf(vv)); }
          zx[((size_t)b*LH + tok)*DPROJ + jj] = vv;
        }
      }
    }
  }
}

// ---------------------------------------------------------------- final LN + head
__global__ void k_head(const float* __restrict__ h, const float* __restrict__ lnw,
                       const float* __restrict__ lnb, const float* __restrict__ hw,
                       const float* __restrict__ hb, float* __restrict__ out) {
  int b = blockIdx.x; int t = threadIdx.x;
  __shared__ float red[2];
  int wave = t >> 6, lane = t & 63;
  float v = h[((size_t)b*LH + LSEQ)*DIM + t];
  float s = v;
  for (int off = 32; off > 0; off >>= 1) s += __shfl_down(s, off);
  if (lane == 0) red[wave] = s;
  __syncthreads();
  float mean = (red[0]+red[1]) / (float)DIM;
  __syncthreads();
  float d = v - mean; float sq = d*d;
  for (int off = 32; off > 0; off >>= 1) sq += __shfl_down(sq, off);
  if (lane == 0) red[wave] = sq;
  __syncthreads();
  float var = (red[0]+red[1]) / (float)DIM;
  float cn = d*rsqrtf(var + 1e-5f)*lnw[t] + lnb[t];
  float dot = cn*hw[t];
  __syncthreads();
  for (int off = 32; off > 0; off >>= 1) dot += __shfl_down(dot, off);
  if (lane == 0) red[wave] = dot;
  __syncthreads();
  if (t == 0) out[b] = red[0]+red[1] + hb[0];
}

extern "C" void kernel_launch(void* const* d_in, const int* in_sizes, int n_in,
                              void* d_out, int out_size, void* d_ws, size_t ws_size,
                              hipStream_t stream) {
  const float* x     = (const float*)d_in[0];
  const float* w1    = (const float*)d_in[1];
  const float* b1    = (const float*)d_in[2];
  const float* w2    = (const float*)d_in[3];
  const float* b2    = (const float*)d_in[4];
  const float* cls   = (const float*)d_in[5];
  const float* inw   = (const float*)d_in[6];   // (4, 644, 128)
  const float* cw    = (const float*)d_in[7];   // (4, 384, 4)
  const float* cb    = (const float*)d_in[8];   // (4, 384)
  const float* dtb   = (const float*)d_in[9];   // (4, 4)
  const float* Alog  = (const float*)d_in[10];  // (4, 4)
  const float* Dh    = (const float*)d_in[11];  // (4, 4)
  const float* nw    = (const float*)d_in[12];  // (4, 256)
  const float* ow    = (const float*)d_in[13];  // (4, 128, 256)
  const float* lnw   = (const float*)d_in[14];
  const float* lnb   = (const float*)d_in[15];
  const float* hw    = (const float*)d_in[16];
  const float* hb    = (const float*)d_in[17];

  float* ws   = (float*)d_ws;
  float* zx   = ws;                                   // 10,535,840
  float* xbc  = zx + (size_t)BATCH*LH*DPROJ;          // 6,282,240
  float* ybuf = xbc + (size_t)BATCH*LH*CONVD;         // 4,194,304 (G aliases ybuf)
  float* G    = ybuf;
  float* Hin  = ybuf + 4194304;                       // 4,194,304
  float* dec  = Hin  + 4194304;                       // 1,024
  unsigned short* hH = (unsigned short*)(dec + 1024);      // 8*2048*128 u16
  unsigned short* hL = hH + (size_t)BATCH*LHP*DIM;         // 8*2048*128 u16
  unsigned short* wH = hL + (size_t)BATCH*LHP*DIM;         // 4*41*4*64*8 u16
  unsigned short* wL = wH + (size_t)DEPTH*NJT*4*64*8;      // same
  unsigned short* oH = wL + (size_t)DEPTH*NJT*4*64*8;      // 4*8*8*64*8 u16
  unsigned short* oL = oH + (size_t)DEPTH*8*8*64*8;        // same
  // total ~27.8M floats-equivalent = ~111 MiB

  float* hout = (float*)d_out + 8;   // final h written directly into output

  k_cast_w<<<(DEPTH*NJT*4*64 + 255)/256, 256, 0, stream>>>(inw, wH, wL);
  k_cast_ow<<<(DEPTH*8*8*64 + 255)/256, 256, 0, stream>>>(ow, oH, oL);

  k_front<<<BATCH*64 + 1, 256, 0, stream>>>(x, w1, b1, w2, b2, cls, hH, hL);
  k_inproj_mfma<<<BATCH*64, 256, 0, stream>>>(hH, hL, wH, wL, dtb, zx);

  for (int i = 0; i < DEPTH; ++i) {
    int doProj = (i < DEPTH-1) ? 1 : 0;
    int nxt = doProj ? (i+1) : 0;
    k_conv<<<(int)(((long)BATCH*LH*(CONVD/4) + 255)/256), 256, 0, stream>>>(
        zx, cw + (size_t)i*CONVD*4, cb + (size_t)i*CONVD, xbc);
    k_chunk_state<<<BATCH*NH*NCH, 256, 0, stream>>>(zx, xbc, Alog + i*NH, G, dec);
    k_combine<<<BATCH*NH*4, 256, 0, stream>>>(G, dec, Hin);
    k_chunk_out<<<BATCH*NH*NCH, 256, 0, stream>>>(zx, xbc, Alog + i*NH, Hin, ybuf);
    k_out_fused<<<BATCH*128, 256, 0, stream>>>(
        ybuf, xbc, zx, Dh + i*NH, nw + (size_t)i*DIN,
        oH + (size_t)i*8*8*64*8, oL + (size_t)i*8*8*64*8,
        wH + (size_t)nxt*NJT*4*64*8, wL + (size_t)nxt*NJT*4*64*8,
        dtb + nxt*NH, hout, doProj);
  }

  k_head<<<BATCH, 128, 0, stream>>>(hout, lnw, lnb, hw, hb, (float*)d_out);
}